// Round 10
// baseline (8062.539 us; speedup 1.0000x reference)
//
#include <hip/hip_runtime.h>
#include <hip/hip_bf16.h>

// Bidirectional 2-layer LSTM, persistent single-kernel implementation.
// I=256, H=512, L=2, D=2, O=8, B=64, S=512.
//
// Round 17 = round 16 re-flight ("container failed twice" matches r9's infra
// signature; r9's re-flight ran fine). Tagged-h rings: data IS the flag.
//  - h stored as u32 {tag:16 | bf16:16} into 4-slot rings (512KB, L2-
//    resident; producer skew structurally <=1 step => ABA-safe with 4 slots).
//  - Consumer polls its own h fragments via `sc1` (device-scope, L1-bypass)
//    dwordx4 loads; tag check via u32-min (tag in high bits); unpack lo16 ->
//    MFMA directly. Deletes producer vmcnt(0) drain, flag stores/arrays, the
//    separate flag poll, and all poll hot-lines.
//  - Hardening vs r16: retry sleeps in slow mode (no IF hard-spin), lim 100K.
// Carried: pinned weights (P1 96, P3 128 regs), LDS x-weights (P3), pre-poll
// x-side MFMA chains, 4-way h-chain split, (256,1), XCD gate (fast=plain
// stores / slow=agent stores), phase fences, bounded waits, memset'd rings.

typedef __attribute__((ext_vector_type(8))) __bf16 bf16x8;
typedef __attribute__((ext_vector_type(4))) float f32x4;
typedef __attribute__((ext_vector_type(4))) unsigned u32x4;

struct Params {
  const float *input_seq, *h0, *c0;
  const float *w_ih_0f, *w_hh_0f, *b_0f;
  const float *w_ih_0b, *w_hh_0b, *b_0b;
  const float *w_ih_1f, *w_hh_1f, *b_1f;
  const float *w_ih_1b, *w_hh_1b, *b_1b;
  const float *fc_w, *fc_b;
  float* out;
  unsigned* flags;        // [0,256): phase slots; [512,768): xcd table
  unsigned* ring0f;       // [4][64][512] u32 {tag|h}: layer0 fwd recurrence
  unsigned* ring0b;       // layer0 bwd
  unsigned* ring1f;       // layer1 fwd
  __bf16* xT;             // [512][64][256]  time-major bf16 input
  __bf16* Wp0f; __bf16* Wp0b;   // [2048 perm rows][768 = 512 hh | 256 ih]
  __bf16* Wp1f; __bf16* Wp1b;   // [2048 perm rows][1536 = 512 hh | 1024 ih]
  __bf16* y0;             // [514][64][1024] bf16; slabs 1..512 = x for P3
  __bf16* h1fout;         // [64][512]  h1f(511) for FC
  __bf16* h1binit;        // [64][512]
  __bf16* h1bout;         // [64][512]
  float* bp;              // [4][2048] permuted biases (0f,0b,1f,1b)
};

__device__ __forceinline__ float sigm(float x) { return 1.f / (1.f + __expf(-x)); }
__device__ __forceinline__ float tanh_fast(float x) {
  return 1.f - 2.f / (1.f + __expf(2.f * x));   // saturates correctly
}
__device__ __forceinline__ void pin(bf16x8& v) { asm volatile("" : "+v"(v)); }

__device__ __forceinline__ unsigned umin4(u32x4 a) {
  unsigned m0 = a[0] < a[1] ? a[0] : a[1];
  unsigned m1 = a[2] < a[3] ? a[2] : a[3];
  return m0 < m1 ? m0 : m1;
}
__device__ __forceinline__ bf16x8 pack_lo(u32x4 a, u32x4 b) {
  union { unsigned u[4]; bf16x8 v; } cv;
  cv.u[0] = (a[0] & 0xffffu) | (a[1] << 16);
  cv.u[1] = (a[2] & 0xffffu) | (a[3] << 16);
  cv.u[2] = (b[0] & 0xffffu) | (b[1] << 16);
  cv.u[3] = (b[2] & 0xffffu) | (b[3] << 16);
  return cv.v;
}

// Phase barrier (3 uses): agent-scope; release fence publishes L2-dirty plain
// stores cross-XCD. Timeout ~200K rounds: deadlock -> clean fail, no wedge.
__device__ __forceinline__ void phase_barrier(unsigned* pf, int wg, int tid, unsigned phase) {
  __syncthreads();
  if (tid == 0) {
    __builtin_amdgcn_fence(__ATOMIC_RELEASE, "agent");
    __hip_atomic_store(pf + wg, phase, __ATOMIC_RELAXED, __HIP_MEMORY_SCOPE_AGENT);
  }
  bool ok;
  unsigned it = 0;
  do {
    unsigned v = __hip_atomic_load(pf + tid, __ATOMIC_RELAXED, __HIP_MEMORY_SCOPE_AGENT);
    ok = (v >= phase) || (++it > 200000u);
    if (!ok) __builtin_amdgcn_s_sleep(8);
  } while (!__syncthreads_and(ok));
  __builtin_amdgcn_fence(__ATOMIC_ACQUIRE, "agent");
}

__device__ __forceinline__ void ring_store(unsigned* a, unsigned v, bool fastm) {
  if (fastm) __hip_atomic_store(a, v, __ATOMIC_RELAXED, __HIP_MEMORY_SCOPE_WORKGROUP);
  else       __hip_atomic_store(a, v, __ATOMIC_RELAXED, __HIP_MEMORY_SCOPE_AGENT);
}

__device__ __forceinline__ unsigned short pointwise_h(f32x4 g4, float& c) {
  float cj = sigm(g4[1]) * c + sigm(g4[0]) * tanh_fast(g4[2]);
  c = cj;
  float h = sigm(g4[3]) * tanh_fast(cj);
  __bf16 hb = (__bf16)h;
  unsigned short hu; __builtin_memcpy(&hu, &hb, 2);
  return hu;
}

__global__ __launch_bounds__(256, 1) void lstm_kernel(Params p) {
  const int tid  = threadIdx.x;
  const int wg   = blockIdx.x;
  const unsigned gtid = wg * 256 + tid;
  const int lane = tid & 63;
  const int wv   = tid >> 6;          // wave 0..3
  const int colq = lane & 15;         // fragment row/col selector
  const int quad = lane >> 4;         // k-subblock selector

  // 64KB static LDS: P3 wfX frags 0..15, wave-private quarter each.
  __shared__ __bf16 wlds[32768];

  // ---------------- prologue: pack/permute/convert ----------------
  { // publish this WG's XCD id (hwreg id=20 HW_REG_XCC_ID)
    unsigned xcd = __builtin_amdgcn_s_getreg(20 | (31 << 11));
    if (tid == 0) p.flags[512 + wg] = xcd;
  }
  { // xT[t][b][:] = bf16(input_seq[b][t][:])
    int row = gtid >> 1, half = gtid & 1;
    int t = row >> 6, b = row & 63;
    const float* src = p.input_seq + ((size_t)b * 512 + t) * 256 + half * 128;
    __bf16* dst = p.xT + (size_t)row * 256 + half * 128;
    for (int i = 0; i < 128; i += 8) {
      bf16x8 v;
      #pragma unroll
      for (int j = 0; j < 8; ++j) v[j] = (__bf16)src[i + j];
      *(bf16x8*)(dst + i) = v;
    }
  }
  // Wp0{f,b}: [2048][768]; perm row rr: u=rr>>2,g=rr&3, orig row R=g*512+u
  for (unsigned task = gtid; task < 2u * 2048 * 6; task += 65536) {
    unsigned dir = task / (2048 * 6);
    unsigned rr = (task / 6) % 2048;
    unsigned ch = task % 6;
    unsigned R = (rr & 3) * 512 + (rr >> 2);
    const float* wih = dir ? p.w_ih_0b : p.w_ih_0f;
    const float* whh = dir ? p.w_hh_0b : p.w_hh_0f;
    __bf16* dst = (dir ? p.Wp0b : p.Wp0f) + (size_t)rr * 768;
    const float* src; unsigned kd;
    if (ch < 4) { src = whh + (size_t)R * 512 + ch * 128;        kd = ch * 128; }
    else        { src = wih + (size_t)R * 256 + (ch - 4) * 128;  kd = 512 + (ch - 4) * 128; }
    for (int i = 0; i < 128; i += 8) {
      bf16x8 v;
      #pragma unroll
      for (int j = 0; j < 8; ++j) v[j] = (__bf16)src[i + j];
      *(bf16x8*)(dst + kd + i) = v;
    }
  }
  // Wp1{f,b}: [2048][1536]
  for (unsigned task = gtid; task < 2u * 2048 * 12; task += 65536) {
    unsigned dir = task / (2048 * 12);
    unsigned rr = (task / 12) % 2048;
    unsigned ch = task % 12;
    unsigned R = (rr & 3) * 512 + (rr >> 2);
    const float* wih = dir ? p.w_ih_1b : p.w_ih_1f;
    const float* whh = dir ? p.w_hh_1b : p.w_hh_1f;
    __bf16* dst = (dir ? p.Wp1b : p.Wp1f) + (size_t)rr * 1536;
    const float* src; unsigned kd;
    if (ch < 4) { src = whh + (size_t)R * 512 + ch * 128;         kd = ch * 128; }
    else        { src = wih + (size_t)R * 1024 + (ch - 4) * 128;  kd = 512 + (ch - 4) * 128; }
    for (int i = 0; i < 128; i += 8) {
      bf16x8 v;
      #pragma unroll
      for (int j = 0; j < 8; ++j) v[j] = (__bf16)src[i + j];
      *(bf16x8*)(dst + kd + i) = v;
    }
  }
  // permuted biases
  if (gtid < 4u * 2048) {
    unsigned arr = gtid >> 11, rr = gtid & 2047;
    unsigned R = (rr & 3) * 512 + (rr >> 2);
    const float* src = arr == 0 ? p.b_0f : arr == 1 ? p.b_0b : arr == 2 ? p.b_1f : p.b_1b;
    p.bp[arr * 2048 + rr] = src[R];
  }
  // h inits: rings slot0 with tag 0 (dl 0..2); h1binit bf16 (dl 3)
  if (gtid < 4u * 4096) {
    unsigned dl = gtid >> 12;
    unsigned e = (gtid & 4095) * 8;
    unsigned b = e >> 9, u = e & 511;
    const float* src = p.h0 + (size_t)dl * 64 * 512 + (size_t)b * 512 + u;
    if (dl == 3) {
      __bf16* dst = p.h1binit + (size_t)b * 512 + u;
      bf16x8 v;
      #pragma unroll
      for (int j = 0; j < 8; ++j) v[j] = (__bf16)src[j];
      *(bf16x8*)dst = v;
    } else {
      unsigned* dst = (dl == 0 ? p.ring0f : dl == 1 ? p.ring0b : p.ring1f) +
                      ((size_t)b * 512 + u);   // slot 0
      #pragma unroll
      for (int j = 0; j < 8; ++j) {
        __bf16 hb = (__bf16)src[j];
        unsigned short hu; __builtin_memcpy(&hu, &hb, 2);
        dst[j] = (unsigned)hu;                 // tag 0 in high16
      }
    }
  }

  phase_barrier(p.flags, wg, tid, 1u);

  // Fast path: residue class on ONE XCD + 8 classes on 8 DISTINCT XCDs.
  bool fast;
  {
    const unsigned* xt = p.flags + 512;
    const int r = wg & 7;
    unsigned x0 = xt[r];
    bool ok = true;
    for (int k = 1; k < 32; ++k) ok &= (xt[r + 8 * k] == x0);
    unsigned mask = 0;
    for (int rr = 0; rr < 8; ++rr) mask |= 1u << (xt[rr] & 31);
    ok &= (__popc(mask) == 8);
    fast = ok;
  }

  // ---------------- P1: layer0 recurrence ----------------
  {
    const int g = wg & 7;
    const bool fwd = g < 4;
    const int bg = g & 3;
    const int ug = wg >> 3;
    const int bbase = bg * 16;
    const int uglob = ug * 16 + wv * 4;
    const int colbase = uglob * 4;
    const __bf16* Wp = fwd ? p.Wp0f : p.Wp0b;
    unsigned* ring = fwd ? p.ring0f : p.ring0b;
    bf16x8 wfH[16], wfI[8];
    #pragma unroll
    for (int kb = 0; kb < 16; ++kb)
      wfH[kb] = *(const bf16x8*)(Wp + (size_t)(colbase + colq) * 768 + kb * 32 + quad * 8);
    #pragma unroll
    for (int kb = 0; kb < 8; ++kb)
      wfI[kb] = *(const bf16x8*)(Wp + (size_t)(colbase + colq) * 768 + 512 + kb * 32 + quad * 8);
    #pragma unroll
    for (int kb = 0; kb < 16; ++kb) pin(wfH[kb]);
    #pragma unroll
    for (int kb = 0; kb < 8; ++kb) pin(wfI[kb]);
    const f32x4 bias4 = *(const f32x4*)(p.bp + (fwd ? 0 : 1) * 2048 + colbase + quad * 4);
    float c = p.c0[(size_t)(fwd ? 0 : 1) * 64 * 512 +
                   (size_t)(bbase + colq) * 512 + uglob + quad];
    const int dcol = fwd ? 0 : 512;
    bool alive = true;
    for (int s = 0; s < 512; ++s) {
      const int t = fwd ? s : 511 - s;
      const __bf16* aX = p.xT + ((size_t)t * 64 + bbase + colq) * 256 + quad * 8;
      // pre-poll: x-side gates
      f32x4 accX = bias4;
      #pragma unroll
      for (int kb = 0; kb < 8; ++kb) {
        bf16x8 xv = *(const bf16x8*)(aX + kb * 32);
        accX = __builtin_amdgcn_mfma_f32_16x16x32_bf16(wfI[kb], xv, accX, 0, 0, 0);
      }
      // poll+fetch h(s-1): tagged ring, device-scope loads (L1-bypass)
      const unsigned gtag = (unsigned)s;
      const unsigned* rowR = ring + (((size_t)(s & 3) * 64 + bbase + colq) * 512);
      u32x4 A[16], Bv[16];
      unsigned lim = alive ? 100000u : 0u;
      unsigned it = 0;
      bool ok;
      do {
        #pragma unroll
        for (int kb = 0; kb < 16; ++kb) {
          const unsigned* pa = rowR + kb * 32 + quad * 8;
          asm volatile("global_load_dwordx4 %0, %1, off sc1" : "=v"(A[kb]) : "v"(pa) : "memory");
          asm volatile("global_load_dwordx4 %0, %1, off sc1" : "=v"(Bv[kb]) : "v"(pa + 4) : "memory");
        }
        asm volatile("s_waitcnt vmcnt(0)" ::: "memory");
        #pragma unroll
        for (int kb = 0; kb < 16; ++kb) asm volatile("" : "+v"(A[kb]), "+v"(Bv[kb]));
        bool f = true;
        #pragma unroll
        for (int kb = 0; kb < 16; ++kb) {
          unsigned ma = umin4(A[kb]), mb = umin4(Bv[kb]);
          unsigned m = ma < mb ? ma : mb;
          f &= ((m >> 16) == gtag);
        }
        ok = (__ballot(f) == ~0ull);
        if (!ok && !fast) __builtin_amdgcn_s_sleep(1);
      } while (!ok && ++it <= lim);
      if (!ok) alive = false;
      // h-side gates (four depth-4 chains), unpack on the fly
      f32x4 a0 = {0.f, 0.f, 0.f, 0.f}, a1 = {0.f, 0.f, 0.f, 0.f};
      f32x4 a2 = {0.f, 0.f, 0.f, 0.f}, a3 = {0.f, 0.f, 0.f, 0.f};
      #pragma unroll
      for (int kb = 0; kb < 4; ++kb) {
        a0 = __builtin_amdgcn_mfma_f32_16x16x32_bf16(wfH[kb],      pack_lo(A[kb],      Bv[kb]),      a0, 0, 0, 0);
        a1 = __builtin_amdgcn_mfma_f32_16x16x32_bf16(wfH[4 + kb],  pack_lo(A[4 + kb],  Bv[4 + kb]),  a1, 0, 0, 0);
        a2 = __builtin_amdgcn_mfma_f32_16x16x32_bf16(wfH[8 + kb],  pack_lo(A[8 + kb],  Bv[8 + kb]),  a2, 0, 0, 0);
        a3 = __builtin_amdgcn_mfma_f32_16x16x32_bf16(wfH[12 + kb], pack_lo(A[12 + kb], Bv[12 + kb]), a3, 0, 0, 0);
      }
      f32x4 g4 = accX + (a0 + a1) + (a2 + a3);
      unsigned short hu = pointwise_h(g4, c);
      // fire-and-forget: tagged ring (critical) + bf16 y0 slab (for P3)
      ring_store(ring + (((size_t)((s + 1) & 3) * 64 + bbase + colq) * 512 + uglob + quad),
                 ((unsigned)(s + 1) << 16) | (unsigned)hu, fast);
      __hip_atomic_store((unsigned short*)(p.y0 + ((size_t)(t + 1) * 64 + bbase + colq) * 1024 + dcol + uglob + quad),
                         hu, __ATOMIC_RELAXED, __HIP_MEMORY_SCOPE_WORKGROUP);
    }
  }
  phase_barrier(p.flags, wg, tid, 2u);

  // ---------------- P3: layer1 fwd ((wg&7)<4) | P4: layer1 bwd single step ----
  if ((wg & 7) < 4) {
    const int bg = wg & 7;
    const int ug = wg >> 3;
    const int bbase = bg * 16;
    const int uglob = ug * 16 + wv * 4;
    const int colbase = uglob * 4;
    bf16x8 wfH[16], wfX2[16];
    #pragma unroll
    for (int kb = 0; kb < 16; ++kb)
      wfH[kb] = *(const bf16x8*)(p.Wp1f + (size_t)(colbase + colq) * 1536 + kb * 32 + quad * 8);
    {
      const __bf16* wsrc = p.Wp1f + (size_t)(colbase + colq) * 1536 + 512;
      #pragma unroll
      for (int kb = 0; kb < 16; ++kb) {
        bf16x8 w = *(const bf16x8*)(wsrc + kb * 32 + quad * 8);
        *(bf16x8*)(wlds + ((size_t)(wv * 16 + kb) * 64 + lane) * 8) = w;
      }
      #pragma unroll
      for (int kb = 0; kb < 16; ++kb)
        wfX2[kb] = *(const bf16x8*)(wsrc + (16 + kb) * 32 + quad * 8);
    }
    #pragma unroll
    for (int kb = 0; kb < 16; ++kb) pin(wfH[kb]);
    #pragma unroll
    for (int kb = 0; kb < 16; ++kb) pin(wfX2[kb]);
    const f32x4 bias4 = *(const f32x4*)(p.bp + 2 * 2048 + colbase + quad * 4);
    float c = p.c0[(size_t)2 * 64 * 512 +
                   (size_t)(bbase + colq) * 512 + uglob + quad];
    bool alive = true;
    for (int t = 0; t < 512; ++t) {
      const __bf16* aX = p.y0 + ((size_t)(t + 1) * 64 + bbase + colq) * 1024 + quad * 8;
      // pre-poll: x-side gates (y0 slab t+1 published at phase 2)
      f32x4 accX0 = bias4, accX1 = {0.f, 0.f, 0.f, 0.f};
      #pragma unroll
      for (int kb = 0; kb < 16; ++kb) {
        bf16x8 xv = *(const bf16x8*)(aX + kb * 32);
        bf16x8 wx = *(const bf16x8*)(wlds + ((size_t)(wv * 16 + kb) * 64 + lane) * 8);
        accX0 = __builtin_amdgcn_mfma_f32_16x16x32_bf16(wx, xv, accX0, 0, 0, 0);
      }
      #pragma unroll
      for (int kb = 0; kb < 16; ++kb) {
        bf16x8 xv = *(const bf16x8*)(aX + (16 + kb) * 32);
        accX1 = __builtin_amdgcn_mfma_f32_16x16x32_bf16(wfX2[kb], xv, accX1, 0, 0, 0);
      }
      // poll+fetch h1f(t-1)
      const unsigned gtag = (unsigned)t;
      const unsigned* rowR = p.ring1f + (((size_t)(t & 3) * 64 + bbase + colq) * 512);
      u32x4 A[16], Bv[16];
      unsigned lim = alive ? 100000u : 0u;
      unsigned it = 0;
      bool ok;
      do {
        #pragma unroll
        for (int kb = 0; kb < 16; ++kb) {
          const unsigned* pa = rowR + kb * 32 + quad * 8;
          asm volatile("global_load_dwordx4 %0, %1, off sc1" : "=v"(A[kb]) : "v"(pa) : "memory");
          asm volatile("global_load_dwordx4 %0, %1, off sc1" : "=v"(Bv[kb]) : "v"(pa + 4) : "memory");
        }
        asm volatile("s_waitcnt vmcnt(0)" ::: "memory");
        #pragma unroll
        for (int kb = 0; kb < 16; ++kb) asm volatile("" : "+v"(A[kb]), "+v"(Bv[kb]));
        bool f = true;
        #pragma unroll
        for (int kb = 0; kb < 16; ++kb) {
          unsigned ma = umin4(A[kb]), mb = umin4(Bv[kb]);
          unsigned m = ma < mb ? ma : mb;
          f &= ((m >> 16) == gtag);
        }
        ok = (__ballot(f) == ~0ull);
        if (!ok && !fast) __builtin_amdgcn_s_sleep(1);
      } while (!ok && ++it <= lim);
      if (!ok) alive = false;
      // h-side gates
      f32x4 a0 = {0.f, 0.f, 0.f, 0.f}, a1 = {0.f, 0.f, 0.f, 0.f};
      f32x4 a2 = {0.f, 0.f, 0.f, 0.f}, a3 = {0.f, 0.f, 0.f, 0.f};
      #pragma unroll
      for (int kb = 0; kb < 4; ++kb) {
        a0 = __builtin_amdgcn_mfma_f32_16x16x32_bf16(wfH[kb],      pack_lo(A[kb],      Bv[kb]),      a0, 0, 0, 0);
        a1 = __builtin_amdgcn_mfma_f32_16x16x32_bf16(wfH[4 + kb],  pack_lo(A[4 + kb],  Bv[4 + kb]),  a1, 0, 0, 0);
        a2 = __builtin_amdgcn_mfma_f32_16x16x32_bf16(wfH[8 + kb],  pack_lo(A[8 + kb],  Bv[8 + kb]),  a2, 0, 0, 0);
        a3 = __builtin_amdgcn_mfma_f32_16x16x32_bf16(wfH[12 + kb], pack_lo(A[12 + kb], Bv[12 + kb]), a3, 0, 0, 0);
      }
      f32x4 g4 = (accX0 + accX1) + (a0 + a1) + (a2 + a3);
      unsigned short hu = pointwise_h(g4, c);
      ring_store(p.ring1f + (((size_t)((t + 1) & 3) * 64 + bbase + colq) * 512 + uglob + quad),
                 ((unsigned)(t + 1) << 16) | (unsigned)hu, fast);
      if (t == 511)
        __hip_atomic_store((unsigned short*)(p.h1fout + (size_t)(bbase + colq) * 512 + uglob + quad),
                           hu, __ATOMIC_RELAXED, __HIP_MEMORY_SCOPE_WORKGROUP);
    }
  } else {
    const int bg = (wg & 7) - 4;
    const int ug = wg >> 3;
    const int bbase = bg * 16;
    const int uglob = ug * 16 + wv * 4;
    const int colbase = uglob * 4;
    const __bf16* aH = p.h1binit + (size_t)(bbase + colq) * 512 + quad * 8;
    const __bf16* aX = p.y0 + ((size_t)512 * 64 + bbase + colq) * 1024 + quad * 8;
    const __bf16* wrow = p.Wp1b + (size_t)(colbase + colq) * 1536;
    const f32x4 bias4 = *(const f32x4*)(p.bp + 3 * 2048 + colbase + quad * 4);
    f32x4 accH = bias4;
    f32x4 accX0 = {0.f, 0.f, 0.f, 0.f}, accX1 = {0.f, 0.f, 0.f, 0.f};
    #pragma unroll
    for (int kb = 0; kb < 16; ++kb)
      accH = __builtin_amdgcn_mfma_f32_16x16x32_bf16(*(const bf16x8*)(wrow + kb * 32 + quad * 8),
                                                     *(const bf16x8*)(aH + kb * 32), accH, 0, 0, 0);
    #pragma unroll
    for (int kb = 0; kb < 16; ++kb)
      accX0 = __builtin_amdgcn_mfma_f32_16x16x32_bf16(*(const bf16x8*)(wrow + (16 + kb) * 32 + quad * 8),
                                                      *(const bf16x8*)(aX + kb * 32), accX0, 0, 0, 0);
    #pragma unroll
    for (int kb = 0; kb < 16; ++kb)
      accX1 = __builtin_amdgcn_mfma_f32_16x16x32_bf16(*(const bf16x8*)(wrow + (32 + kb) * 32 + quad * 8),
                                                      *(const bf16x8*)(aX + (16 + kb) * 32), accX1, 0, 0, 0);
    f32x4 g4 = accH + accX0 + accX1;
    float c = p.c0[(size_t)3 * 64 * 512 +
                   (size_t)(bbase + colq) * 512 + uglob + quad];
    unsigned short hu = pointwise_h(g4, c);
    __hip_atomic_store((unsigned short*)(p.h1bout + (size_t)(bbase + colq) * 512 + uglob + quad),
                       hu, __ATOMIC_RELAXED, __HIP_MEMORY_SCOPE_WORKGROUP);
  }
  phase_barrier(p.flags, wg, tid, 3u);

  // ---------------- FC: out[b][o] = fc_b[o] + last[b,:] . fc_w[o,:] ----------
  if (wg < 8) {
    const int b = wg * 8 + (tid >> 5);
    const int o = (tid >> 2) & 7;
    const int ks = tid & 3;
    const int k0 = ks * 256;
    const __bf16* l1 = p.h1fout + (size_t)b * 512;             // h1f(t=511)
    const __bf16* l2 = p.h1bout + (size_t)b * 512;             // h1b(t=511)
    const __bf16* hsrc = (ks < 2) ? (l1 + k0) : (l2 + k0 - 512);
    const float* w = p.fc_w + (size_t)o * 1024 + k0;
    float acc = 0.f;
    for (int k = 0; k < 256; ++k) acc += (float)hsrc[k] * w[k];
    acc += __shfl_down(acc, 2, 4);
    acc += __shfl_down(acc, 1, 4);
    if (ks == 0) p.out[b * 8 + o] = acc + p.fc_b[o];
  }
}

extern "C" void kernel_launch(void* const* d_in, const int* in_sizes, int n_in,
                              void* d_out, int out_size, void* d_ws, size_t ws_size,
                              hipStream_t stream) {
  char* ws = (char*)d_ws;
  Params p;
  p.input_seq = (const float*)d_in[0];
  p.h0 = (const float*)d_in[1];
  p.c0 = (const float*)d_in[2];
  p.w_ih_0f = (const float*)d_in[3];  p.w_hh_0f = (const float*)d_in[4];  p.b_0f = (const float*)d_in[5];
  p.w_ih_0b = (const float*)d_in[6];  p.w_hh_0b = (const float*)d_in[7];  p.b_0b = (const float*)d_in[8];
  p.w_ih_1f = (const float*)d_in[9];  p.w_hh_1f = (const float*)d_in[10]; p.b_1f = (const float*)d_in[11];
  p.w_ih_1b = (const float*)d_in[12]; p.w_hh_1b = (const float*)d_in[13]; p.b_1b = (const float*)d_in[14];
  p.fc_w = (const float*)d_in[15];    p.fc_b = (const float*)d_in[16];
  p.out = (float*)d_out;

  const size_t RING_BYTES = (size_t)4 * 64 * 512 * 4;   // 524288
  const size_t SYNC_BYTES = 4096 + 3 * RING_BYTES;      // flags + rings (tags!)
  size_t off = 0;
  p.flags  = (unsigned*)(ws + off); off += 4096;
  p.ring0f = (unsigned*)(ws + off); off += RING_BYTES;
  p.ring0b = (unsigned*)(ws + off); off += RING_BYTES;
  p.ring1f = (unsigned*)(ws + off); off += RING_BYTES;
  p.xT     = (__bf16*)(ws + off);   off += (size_t)512 * 64 * 256 * 2;
  p.Wp0f   = (__bf16*)(ws + off);   off += (size_t)2048 * 768 * 2;
  p.Wp0b   = (__bf16*)(ws + off);   off += (size_t)2048 * 768 * 2;
  p.Wp1f   = (__bf16*)(ws + off);   off += (size_t)2048 * 1536 * 2;
  p.Wp1b   = (__bf16*)(ws + off);   off += (size_t)2048 * 1536 * 2;
  p.y0     = (__bf16*)(ws + off);   off += (size_t)514 * 64 * 1024 * 2;
  p.h1fout = (__bf16*)(ws + off);   off += (size_t)64 * 512 * 2;
  p.h1binit= (__bf16*)(ws + off);   off += (size_t)64 * 512 * 2;
  p.h1bout = (__bf16*)(ws + off);   off += (size_t)64 * 512 * 2;
  p.bp     = (float*)(ws + off);    off += (size_t)4 * 2048 * 4;
  (void)ws_size; (void)in_sizes; (void)n_in; (void)out_size;

  hipMemsetAsync(d_ws, 0, SYNC_BYTES, stream);   // zero phase flags + ring tags
  lstm_kernel<<<dim3(256), dim3(256), 0, stream>>>(p);
}

// Round 11
// 5442.321 us; speedup vs baseline: 1.4815x; 1.4815x over previous
//
#include <hip/hip_runtime.h>
#include <hip/hip_bf16.h>

// Bidirectional 2-layer LSTM, persistent single-kernel implementation.
// I=256, H=512, L=2, D=2, O=8, B=64, S=512.
//
// Round 18 = r15 (best, 5510us) + producer-publish fixes. r17's tagged-ring
// regressed (+2.6us/hop): `sc1` loads are SYSTEM-scope on gfx950 -> forced
// L2 miss, IF RTT per 512B/lane poll round. Scope ladder now fully mapped:
// plain=L1-stale-risk, sc0=stale (r10), sc1=IF (r17); only compiler
// agent-scope atomic loads are prompt+fast (r11/r15). So: separated
// flag+data handshake (r15) with the publish leg tightened:
//  - h stores re-packed 4-lanes->u64 via shfl (16x8B/wave, r12-proven)
//    instead of r14/r15's 64x2B scatter: fewer write-through L2
//    transactions inside the vmcnt(0) that gates the flag store.
//  - sched_barrier(0) after the flag store: stops the compiler hoisting
//    next-iteration x prefetches above the drain (they fattened the
//    vmcnt(0) and delayed flag publication every step).
// Carried from r15: pinned weights (P1 96, P3 128 regs), LDS x-weights
// (P3), pre-poll x-side MFMA chains, 4-way h-chain split, per-wave flags,
// no per-step __syncthreads, (256,1), XCD gate (fast=plain stores /
// slow=agent stores), agent-scope polls, phase fences, bounded waits.

typedef __attribute__((ext_vector_type(8))) __bf16 bf16x8;
typedef __attribute__((ext_vector_type(4))) float f32x4;

struct Params {
  const float *input_seq, *h0, *c0;
  const float *w_ih_0f, *w_hh_0f, *b_0f;
  const float *w_ih_0b, *w_hh_0b, *b_0b;
  const float *w_ih_1f, *w_hh_1f, *b_1f;
  const float *w_ih_1b, *w_hh_1b, *b_1b;
  const float *fc_w, *fc_b;
  float* out;
  unsigned* flags;        // [0,256): phase slots; [512,768): xcd table
  unsigned* stepf;        // [12 groups][128 producer-waves][16 u32], 64B/line
  __bf16* xT;             // [512][64][256]  time-major bf16 input
  __bf16* Wp0f; __bf16* Wp0b;   // [2048 perm rows][768 = 512 hh | 256 ih]
  __bf16* Wp1f; __bf16* Wp1b;   // [2048 perm rows][1536 = 512 hh | 1024 ih]
  __bf16* y0;             // [514][64][1024]; slab s = t+1; slab0/513 = inits
  __bf16* y1f;            // [513][64][512]; slab t+1 = h1f(t); slab0 = init
  __bf16* h1binit;        // [64][512]
  __bf16* h1bout;         // [64][512]
  float* bp;              // [4][2048] permuted biases (0f,0b,1f,1b)
};

__device__ __forceinline__ float sigm(float x) { return 1.f / (1.f + __expf(-x)); }
__device__ __forceinline__ float tanh_fast(float x) {
  return 1.f - 2.f / (1.f + __expf(2.f * x));   // saturates correctly
}
__device__ __forceinline__ void pin(bf16x8& v) { asm volatile("" : "+v"(v)); }

// Phase barrier (3 uses): agent-scope; release fence publishes L2-dirty plain
// stores cross-XCD. Timeout ~200K rounds: deadlock -> clean fail, no wedge.
__device__ __forceinline__ void phase_barrier(unsigned* pf, int wg, int tid, unsigned phase) {
  __syncthreads();
  if (tid == 0) {
    __builtin_amdgcn_fence(__ATOMIC_RELEASE, "agent");
    __hip_atomic_store(pf + wg, phase, __ATOMIC_RELAXED, __HIP_MEMORY_SCOPE_AGENT);
  }
  bool ok;
  unsigned it = 0;
  do {
    unsigned v = __hip_atomic_load(pf + tid, __ATOMIC_RELAXED, __HIP_MEMORY_SCOPE_AGENT);
    ok = (v >= phase) || (++it > 200000u);
    if (!ok) __builtin_amdgcn_s_sleep(8);
  } while (!__syncthreads_and(ok));
  __builtin_amdgcn_fence(__ATOMIC_ACQUIRE, "agent");
}

// Every wave polls 128 producer-wave flag lines (2 per lane, 64B stride).
// Agent-scope loads (L1-bypass, prompt; same-XCD L2-served in fast mode).
__device__ __forceinline__ bool group_wait128(const unsigned* base, int lane,
                                              unsigned need, bool fast) {
  for (unsigned it = 0;; ++it) {
    unsigned v0 = __hip_atomic_load(base + (size_t)lane * 16, __ATOMIC_RELAXED,
                                    __HIP_MEMORY_SCOPE_AGENT);
    unsigned v1 = __hip_atomic_load(base + (size_t)(lane + 64) * 16, __ATOMIC_RELAXED,
                                    __HIP_MEMORY_SCOPE_AGENT);
    bool ok = (v0 >= need) && (v1 >= need);
    if (__ballot(ok) == ~0ull) break;
    if (it > 1000000u) return false;
    if (!fast) __builtin_amdgcn_s_sleep(1);
  }
  asm volatile("" ::: "memory");   // no hoisting of h loads above the poll
  return true;
}

__device__ __forceinline__ void flag_store(unsigned* a, unsigned v, bool fast) {
  if (fast) __hip_atomic_store(a, v, __ATOMIC_RELAXED, __HIP_MEMORY_SCOPE_WORKGROUP);
  else      __hip_atomic_store(a, v, __ATOMIC_RELAXED, __HIP_MEMORY_SCOPE_AGENT);
}

// Pointwise, transposed-gate form, PACKED store: lane (q=lane>>4, cb=lane&15)
// holds gates {i,f,g,o} of (unit uglob+q, batch bbase+cb) in g4[0..3].
// Pack the 4 units of one batch row (lanes cb, cb+16, cb+32, cb+48) into one
// u64; lanes <16 store 8B at row (bbase+lane), col uglob. 16 transactions/
// wave vs 64 scattered 2B stores -- smaller vmcnt(0) drain before the flag.
// Returns this lane's bf16 h bits (for off-path mirrors).
__device__ __forceinline__ unsigned short pointwise_pack(f32x4 g4, int lane, float& c,
                                                         __bf16* rowbase0, int stride,
                                                         bool fast) {
  float cj = sigm(g4[1]) * c + sigm(g4[0]) * tanh_fast(g4[2]);
  c = cj;
  float h = sigm(g4[3]) * tanh_fast(cj);
  __bf16 hb = (__bf16)h;
  unsigned short hu; __builtin_memcpy(&hu, &hb, 2);
  unsigned v0 = (unsigned)hu | (__shfl_down((unsigned)hu, 16) << 16);
  unsigned long long pk = (unsigned long long)v0 |
                          ((unsigned long long)__shfl_down(v0, 32) << 32);
  if (lane < 16) {
    unsigned long long* dst = (unsigned long long*)(rowbase0 + (size_t)lane * stride);
    if (fast)
      __hip_atomic_store(dst, pk, __ATOMIC_RELAXED, __HIP_MEMORY_SCOPE_WORKGROUP);
    else
      __hip_atomic_store(dst, pk, __ATOMIC_RELAXED, __HIP_MEMORY_SCOPE_AGENT);
  }
  return hu;
}

__global__ __launch_bounds__(256, 1) void lstm_kernel(Params p) {
  const int tid  = threadIdx.x;
  const int wg   = blockIdx.x;
  const unsigned gtid = wg * 256 + tid;
  const int lane = tid & 63;
  const int wv   = tid >> 6;          // wave 0..3
  const int colq = lane & 15;         // fragment row/col selector
  const int quad = lane >> 4;         // k-subblock selector

  // 64KB static LDS: P3 wfX frags 0..15, wave-private quarter each.
  __shared__ __bf16 wlds[32768];

  // ---------------- prologue: pack/permute/convert ----------------
  { // publish this WG's XCD id (hwreg id=20 HW_REG_XCC_ID)
    unsigned xcd = __builtin_amdgcn_s_getreg(20 | (31 << 11));
    if (tid == 0) p.flags[512 + wg] = xcd;
  }
  { // xT[t][b][:] = bf16(input_seq[b][t][:])
    int row = gtid >> 1, half = gtid & 1;
    int t = row >> 6, b = row & 63;
    const float* src = p.input_seq + ((size_t)b * 512 + t) * 256 + half * 128;
    __bf16* dst = p.xT + (size_t)row * 256 + half * 128;
    for (int i = 0; i < 128; i += 8) {
      bf16x8 v;
      #pragma unroll
      for (int j = 0; j < 8; ++j) v[j] = (__bf16)src[i + j];
      *(bf16x8*)(dst + i) = v;
    }
  }
  // Wp0{f,b}: [2048][768]; perm row rr: u=rr>>2,g=rr&3, orig row R=g*512+u
  for (unsigned task = gtid; task < 2u * 2048 * 6; task += 65536) {
    unsigned dir = task / (2048 * 6);
    unsigned rr = (task / 6) % 2048;
    unsigned ch = task % 6;
    unsigned R = (rr & 3) * 512 + (rr >> 2);
    const float* wih = dir ? p.w_ih_0b : p.w_ih_0f;
    const float* whh = dir ? p.w_hh_0b : p.w_hh_0f;
    __bf16* dst = (dir ? p.Wp0b : p.Wp0f) + (size_t)rr * 768;
    const float* src; unsigned kd;
    if (ch < 4) { src = whh + (size_t)R * 512 + ch * 128;        kd = ch * 128; }
    else        { src = wih + (size_t)R * 256 + (ch - 4) * 128;  kd = 512 + (ch - 4) * 128; }
    for (int i = 0; i < 128; i += 8) {
      bf16x8 v;
      #pragma unroll
      for (int j = 0; j < 8; ++j) v[j] = (__bf16)src[i + j];
      *(bf16x8*)(dst + kd + i) = v;
    }
  }
  // Wp1{f,b}: [2048][1536]
  for (unsigned task = gtid; task < 2u * 2048 * 12; task += 65536) {
    unsigned dir = task / (2048 * 12);
    unsigned rr = (task / 12) % 2048;
    unsigned ch = task % 12;
    unsigned R = (rr & 3) * 512 + (rr >> 2);
    const float* wih = dir ? p.w_ih_1b : p.w_ih_1f;
    const float* whh = dir ? p.w_hh_1b : p.w_hh_1f;
    __bf16* dst = (dir ? p.Wp1b : p.Wp1f) + (size_t)rr * 1536;
    const float* src; unsigned kd;
    if (ch < 4) { src = whh + (size_t)R * 512 + ch * 128;         kd = ch * 128; }
    else        { src = wih + (size_t)R * 1024 + (ch - 4) * 128;  kd = 512 + (ch - 4) * 128; }
    for (int i = 0; i < 128; i += 8) {
      bf16x8 v;
      #pragma unroll
      for (int j = 0; j < 8; ++j) v[j] = (__bf16)src[i + j];
      *(bf16x8*)(dst + kd + i) = v;
    }
  }
  // permuted biases
  if (gtid < 4u * 2048) {
    unsigned arr = gtid >> 11, rr = gtid & 2047;
    unsigned R = (rr & 3) * 512 + (rr >> 2);
    const float* src = arr == 0 ? p.b_0f : arr == 1 ? p.b_0b : arr == 2 ? p.b_1f : p.b_1b;
    p.bp[arr * 2048 + rr] = src[R];
  }
  // h inits
  if (gtid < 4u * 4096) {
    unsigned dl = gtid >> 12;
    unsigned e = (gtid & 4095) * 8;
    unsigned b = e >> 9, u = e & 511;
    const float* src = p.h0 + (size_t)dl * 64 * 512 + (size_t)b * 512 + u;
    __bf16* dst;
    if (dl == 0)      dst = p.y0 + ((size_t)0 * 64 + b) * 1024 + u;
    else if (dl == 1) dst = p.y0 + ((size_t)513 * 64 + b) * 1024 + 512 + u;
    else if (dl == 2) dst = p.y1f + ((size_t)0 * 64 + b) * 512 + u;
    else              dst = p.h1binit + (size_t)b * 512 + u;
    bf16x8 v;
    #pragma unroll
    for (int j = 0; j < 8; ++j) v[j] = (__bf16)src[j];
    *(bf16x8*)dst = v;
  }

  phase_barrier(p.flags, wg, tid, 1u);

  // Fast path: residue class on ONE XCD + 8 classes on 8 DISTINCT XCDs.
  bool fast;
  {
    const unsigned* xt = p.flags + 512;
    const int r = wg & 7;
    unsigned x0 = xt[r];
    bool ok = true;
    for (int k = 1; k < 32; ++k) ok &= (xt[r + 8 * k] == x0);
    unsigned mask = 0;
    for (int rr = 0; rr < 8; ++rr) mask |= 1u << (xt[rr] & 31);
    ok &= (__popc(mask) == 8);
    fast = ok;
  }

  // ---------------- P1: layer0 recurrence ----------------
  {
    const int g = wg & 7;
    const bool fwd = g < 4;
    const int bg = g & 3;
    const int ug = wg >> 3;
    const int bbase = bg * 16;
    const int uglob = ug * 16 + wv * 4;
    const int colbase = uglob * 4;
    const __bf16* Wp = fwd ? p.Wp0f : p.Wp0b;
    bf16x8 wfH[16], wfI[8];
    #pragma unroll
    for (int kb = 0; kb < 16; ++kb)
      wfH[kb] = *(const bf16x8*)(Wp + (size_t)(colbase + colq) * 768 + kb * 32 + quad * 8);
    #pragma unroll
    for (int kb = 0; kb < 8; ++kb)
      wfI[kb] = *(const bf16x8*)(Wp + (size_t)(colbase + colq) * 768 + 512 + kb * 32 + quad * 8);
    #pragma unroll
    for (int kb = 0; kb < 16; ++kb) pin(wfH[kb]);
    #pragma unroll
    for (int kb = 0; kb < 8; ++kb) pin(wfI[kb]);
    const f32x4 bias4 = *(const f32x4*)(p.bp + (fwd ? 0 : 1) * 2048 + colbase + quad * 4);
    float c = p.c0[(size_t)(fwd ? 0 : 1) * 64 * 512 +
                   (size_t)(bbase + colq) * 512 + uglob + quad];
    const int dcol = fwd ? 0 : 512;
    unsigned* gfl = p.stepf + (size_t)g * 128 * 16;
    bool alive = true;
    for (int s = 0; s < 512; ++s) {
      const int t = fwd ? s : 511 - s;
      const int slabA = fwd ? t : t + 2;
      const __bf16* aX = p.xT + ((size_t)t * 64 + bbase + colq) * 256 + quad * 8;
      // pre-poll: x-side gates (x is static input)
      f32x4 accX = bias4;
      #pragma unroll
      for (int kb = 0; kb < 8; ++kb) {
        bf16x8 xv = *(const bf16x8*)(aX + kb * 32);
        accX = __builtin_amdgcn_mfma_f32_16x16x32_bf16(wfI[kb], xv, accX, 0, 0, 0);
      }
      if (s > 0 && alive) alive = group_wait128(gfl, lane, (unsigned)s, fast);
      // post-poll: h-side gates (four depth-4 chains)
      const __bf16* aH = p.y0 + ((size_t)slabA * 64 + bbase + colq) * 1024 + dcol + quad * 8;
      f32x4 a0 = {0.f, 0.f, 0.f, 0.f}, a1 = {0.f, 0.f, 0.f, 0.f};
      f32x4 a2 = {0.f, 0.f, 0.f, 0.f}, a3 = {0.f, 0.f, 0.f, 0.f};
      #pragma unroll
      for (int kb = 0; kb < 4; ++kb) {
        a0 = __builtin_amdgcn_mfma_f32_16x16x32_bf16(wfH[kb],      *(const bf16x8*)(aH + kb * 32),        a0, 0, 0, 0);
        a1 = __builtin_amdgcn_mfma_f32_16x16x32_bf16(wfH[4 + kb],  *(const bf16x8*)(aH + (4 + kb) * 32),  a1, 0, 0, 0);
        a2 = __builtin_amdgcn_mfma_f32_16x16x32_bf16(wfH[8 + kb],  *(const bf16x8*)(aH + (8 + kb) * 32),  a2, 0, 0, 0);
        a3 = __builtin_amdgcn_mfma_f32_16x16x32_bf16(wfH[12 + kb], *(const bf16x8*)(aH + (12 + kb) * 32), a3, 0, 0, 0);
      }
      f32x4 g4 = accX + (a0 + a1) + (a2 + a3);
      pointwise_pack(g4, lane, c,
        p.y0 + ((size_t)(t + 1) * 64 + bbase) * 1024 + dcol + uglob, 1024, fast);
      if (s < 511) {
        asm volatile("s_waitcnt vmcnt(0)" ::: "memory");  // h stores at L2/IF
        if (lane == 0)
          flag_store(gfl + (size_t)(ug * 4 + wv) * 16, (unsigned)(s + 1), fast);
        __builtin_amdgcn_sched_barrier(0);  // keep next-iter prefetch below flag
      }
    }
  }
  phase_barrier(p.flags, wg, tid, 2u);

  // ---------------- P3: layer1 fwd ((wg&7)<4) | P4: layer1 bwd single step ----
  if ((wg & 7) < 4) {
    const int bg = wg & 7;
    const int ug = wg >> 3;
    const int bbase = bg * 16;
    const int uglob = ug * 16 + wv * 4;
    const int colbase = uglob * 4;
    bf16x8 wfH[16], wfX2[16];
    #pragma unroll
    for (int kb = 0; kb < 16; ++kb)
      wfH[kb] = *(const bf16x8*)(p.Wp1f + (size_t)(colbase + colq) * 1536 + kb * 32 + quad * 8);
    {
      const __bf16* wsrc = p.Wp1f + (size_t)(colbase + colq) * 1536 + 512;
      #pragma unroll
      for (int kb = 0; kb < 16; ++kb) {
        bf16x8 w = *(const bf16x8*)(wsrc + kb * 32 + quad * 8);
        *(bf16x8*)(wlds + ((size_t)(wv * 16 + kb) * 64 + lane) * 8) = w;
      }
      #pragma unroll
      for (int kb = 0; kb < 16; ++kb)
        wfX2[kb] = *(const bf16x8*)(wsrc + (16 + kb) * 32 + quad * 8);
    }
    #pragma unroll
    for (int kb = 0; kb < 16; ++kb) pin(wfH[kb]);
    #pragma unroll
    for (int kb = 0; kb < 16; ++kb) pin(wfX2[kb]);
    const f32x4 bias4 = *(const f32x4*)(p.bp + 2 * 2048 + colbase + quad * 4);
    float c = p.c0[(size_t)2 * 64 * 512 +
                   (size_t)(bbase + colq) * 512 + uglob + quad];
    unsigned* gfl = p.stepf + (size_t)(8 + bg) * 128 * 16;
    bool alive = true;
    for (int t = 0; t < 512; ++t) {
      const __bf16* aX = p.y0 + ((size_t)(t + 1) * 64 + bbase + colq) * 1024 + quad * 8;
      // pre-poll: x-side gates (y0 slab t+1 published at phase 2)
      f32x4 accX0 = bias4, accX1 = {0.f, 0.f, 0.f, 0.f};
      #pragma unroll
      for (int kb = 0; kb < 16; ++kb) {
        bf16x8 xv = *(const bf16x8*)(aX + kb * 32);
        bf16x8 wx = *(const bf16x8*)(wlds + ((size_t)(wv * 16 + kb) * 64 + lane) * 8);
        accX0 = __builtin_amdgcn_mfma_f32_16x16x32_bf16(wx, xv, accX0, 0, 0, 0);
      }
      #pragma unroll
      for (int kb = 0; kb < 16; ++kb) {
        bf16x8 xv = *(const bf16x8*)(aX + (16 + kb) * 32);
        accX1 = __builtin_amdgcn_mfma_f32_16x16x32_bf16(wfX2[kb], xv, accX1, 0, 0, 0);
      }
      if (t > 0 && alive) alive = group_wait128(gfl, lane, (unsigned)t, fast);
      // post-poll: h-side gates (four depth-4 chains)
      const __bf16* aH = p.y1f + ((size_t)t * 64 + bbase + colq) * 512 + quad * 8;
      f32x4 a0 = {0.f, 0.f, 0.f, 0.f}, a1 = {0.f, 0.f, 0.f, 0.f};
      f32x4 a2 = {0.f, 0.f, 0.f, 0.f}, a3 = {0.f, 0.f, 0.f, 0.f};
      #pragma unroll
      for (int kb = 0; kb < 4; ++kb) {
        a0 = __builtin_amdgcn_mfma_f32_16x16x32_bf16(wfH[kb],      *(const bf16x8*)(aH + kb * 32),        a0, 0, 0, 0);
        a1 = __builtin_amdgcn_mfma_f32_16x16x32_bf16(wfH[4 + kb],  *(const bf16x8*)(aH + (4 + kb) * 32),  a1, 0, 0, 0);
        a2 = __builtin_amdgcn_mfma_f32_16x16x32_bf16(wfH[8 + kb],  *(const bf16x8*)(aH + (8 + kb) * 32),  a2, 0, 0, 0);
        a3 = __builtin_amdgcn_mfma_f32_16x16x32_bf16(wfH[12 + kb], *(const bf16x8*)(aH + (12 + kb) * 32), a3, 0, 0, 0);
      }
      f32x4 g4 = (accX0 + accX1) + (a0 + a1) + (a2 + a3);
      pointwise_pack(g4, lane, c,
        p.y1f + ((size_t)(t + 1) * 64 + bbase) * 512 + uglob, 512, fast);
      if (t < 511) {
        asm volatile("s_waitcnt vmcnt(0)" ::: "memory");
        if (lane == 0)
          flag_store(gfl + (size_t)(ug * 4 + wv) * 16, (unsigned)(t + 1), fast);
        __builtin_amdgcn_sched_barrier(0);
      }
    }
  } else {
    const int bg = (wg & 7) - 4;
    const int ug = wg >> 3;
    const int bbase = bg * 16;
    const int uglob = ug * 16 + wv * 4;
    const int colbase = uglob * 4;
    const __bf16* aH = p.h1binit + (size_t)(bbase + colq) * 512 + quad * 8;
    const __bf16* aX = p.y0 + ((size_t)512 * 64 + bbase + colq) * 1024 + quad * 8;
    const __bf16* wrow = p.Wp1b + (size_t)(colbase + colq) * 1536;
    const f32x4 bias4 = *(const f32x4*)(p.bp + 3 * 2048 + colbase + quad * 4);
    f32x4 accH = bias4;
    f32x4 accX0 = {0.f, 0.f, 0.f, 0.f}, accX1 = {0.f, 0.f, 0.f, 0.f};
    #pragma unroll
    for (int kb = 0; kb < 16; ++kb)
      accH = __builtin_amdgcn_mfma_f32_16x16x32_bf16(*(const bf16x8*)(wrow + kb * 32 + quad * 8),
                                                     *(const bf16x8*)(aH + kb * 32), accH, 0, 0, 0);
    #pragma unroll
    for (int kb = 0; kb < 16; ++kb)
      accX0 = __builtin_amdgcn_mfma_f32_16x16x32_bf16(*(const bf16x8*)(wrow + (16 + kb) * 32 + quad * 8),
                                                      *(const bf16x8*)(aX + kb * 32), accX0, 0, 0, 0);
    #pragma unroll
    for (int kb = 0; kb < 16; ++kb)
      accX1 = __builtin_amdgcn_mfma_f32_16x16x32_bf16(*(const bf16x8*)(wrow + (32 + kb) * 32 + quad * 8),
                                                      *(const bf16x8*)(aX + (16 + kb) * 32), accX1, 0, 0, 0);
    f32x4 g4 = accH + accX0 + accX1;
    float c = p.c0[(size_t)3 * 64 * 512 +
                   (size_t)(bbase + colq) * 512 + uglob + quad];
    pointwise_pack(g4, lane, c,
      p.h1bout + (size_t)bbase * 512 + uglob, 512, true);
  }
  phase_barrier(p.flags, wg, tid, 3u);

  // ---------------- FC: out[b][o] = fc_b[o] + last[b,:] . fc_w[o,:] ----------
  if (wg < 8) {
    const int b = wg * 8 + (tid >> 5);
    const int o = (tid >> 2) & 7;
    const int ks = tid & 3;
    const int k0 = ks * 256;
    const __bf16* l1 = p.y1f + ((size_t)512 * 64 + b) * 512;   // h1f(t=511)
    const __bf16* l2 = p.h1bout + (size_t)b * 512;             // h1b(t=511)
    const __bf16* hsrc = (ks < 2) ? (l1 + k0) : (l2 + k0 - 512);
    const float* w = p.fc_w + (size_t)o * 1024 + k0;
    float acc = 0.f;
    for (int k = 0; k < 256; ++k) acc += (float)hsrc[k] * w[k];
    acc += __shfl_down(acc, 2, 4);
    acc += __shfl_down(acc, 1, 4);
    if (ks == 0) p.out[b * 8 + o] = acc + p.fc_b[o];
  }
}

extern "C" void kernel_launch(void* const* d_in, const int* in_sizes, int n_in,
                              void* d_out, int out_size, void* d_ws, size_t ws_size,
                              hipStream_t stream) {
  char* ws = (char*)d_ws;
  Params p;
  p.input_seq = (const float*)d_in[0];
  p.h0 = (const float*)d_in[1];
  p.c0 = (const float*)d_in[2];
  p.w_ih_0f = (const float*)d_in[3];  p.w_hh_0f = (const float*)d_in[4];  p.b_0f = (const float*)d_in[5];
  p.w_ih_0b = (const float*)d_in[6];  p.w_hh_0b = (const float*)d_in[7];  p.b_0b = (const float*)d_in[8];
  p.w_ih_1f = (const float*)d_in[9];  p.w_hh_1f = (const float*)d_in[10]; p.b_1f = (const float*)d_in[11];
  p.w_ih_1b = (const float*)d_in[12]; p.w_hh_1b = (const float*)d_in[13]; p.b_1b = (const float*)d_in[14];
  p.fc_w = (const float*)d_in[15];    p.fc_b = (const float*)d_in[16];
  p.out = (float*)d_out;

  const size_t STEPF_BYTES = (size_t)12 * 128 * 64;  // 98304
  const size_t SYNC_BYTES = 4096 + STEPF_BYTES;
  size_t off = 0;
  p.flags  = (unsigned*)(ws + off); off += 4096;
  p.stepf  = (unsigned*)(ws + off); off += STEPF_BYTES;
  p.xT     = (__bf16*)(ws + off);   off += (size_t)512 * 64 * 256 * 2;
  p.Wp0f   = (__bf16*)(ws + off);   off += (size_t)2048 * 768 * 2;
  p.Wp0b   = (__bf16*)(ws + off);   off += (size_t)2048 * 768 * 2;
  p.Wp1f   = (__bf16*)(ws + off);   off += (size_t)2048 * 1536 * 2;
  p.Wp1b   = (__bf16*)(ws + off);   off += (size_t)2048 * 1536 * 2;
  p.y0     = (__bf16*)(ws + off);   off += (size_t)514 * 64 * 1024 * 2;
  p.y1f    = (__bf16*)(ws + off);   off += (size_t)513 * 64 * 512 * 2;
  p.h1binit= (__bf16*)(ws + off);   off += (size_t)64 * 512 * 2;
  p.h1bout = (__bf16*)(ws + off);   off += (size_t)64 * 512 * 2;
  p.bp     = (float*)(ws + off);    off += (size_t)4 * 2048 * 4;
  (void)ws_size; (void)in_sizes; (void)n_in; (void)out_size;

  hipMemsetAsync(d_ws, 0, SYNC_BYTES, stream);   // zero phase flags + step flags
  lstm_kernel<<<dim3(256), dim3(256), 0, stream>>>(p);
}